// Round 13
// baseline (2580.959 us; speedup 1.0000x reference)
//
#include <hip/hip_runtime.h>
#include <hip/hip_fp16.h>

#define B_ 256
#define T_ 1200
#define I_ 16
#define H_ 128

typedef __attribute__((ext_vector_type(2))) _Float16 h2;
typedef __attribute__((ext_vector_type(8))) _Float16 f16x8;

union f16x8u { f16x8 v; h2 h[4]; _Float16 s[8]; };
union h2i { h2 h; int i; };

#if __has_builtin(__builtin_amdgcn_fdot2)
__device__ __forceinline__ float fdot2(h2 a, h2 b, float c) {
  return __builtin_amdgcn_fdot2(a, b, c, false);  // v_dot2_f32_f16
}
#else
__device__ __forceinline__ float fdot2(h2 a, h2 b, float c) {
  return fmaf((float)a.x, (float)b.x, fmaf((float)a.y, (float)b.y, c));
}
#endif

template <int PAT>
__device__ __forceinline__ float qbcast(float x) {
  return __int_as_float(__builtin_amdgcn_update_dpp(0, __float_as_int(x), PAT, 0xF, 0xF, true));
}

__device__ __forceinline__ float wred(float x) {
  x += __int_as_float(__builtin_amdgcn_update_dpp(0, __float_as_int(x), 0x141, 0xF, 0xF, true)); // row_half_mirror ~ xor4
  x += __int_as_float(__builtin_amdgcn_update_dpp(0, __float_as_int(x), 0x140, 0xF, 0xF, true)); // row_mirror ~ xor8
  x += __shfl_xor(x, 16);
  x += __shfl_xor(x, 32);
  return x;
}

__device__ __forceinline__ float tanh_(float x) {
  return 1.f - 2.f * __builtin_amdgcn_rcpf(1.f + __expf(2.f * x));
}

__device__ __forceinline__ void load_row_h2(const float* __restrict__ p, h2* w) {
#pragma unroll
  for (int i = 0; i < 32; ++i) {
    const float4 v = *(const float4*)(p + 4 * i);
    w[2 * i].x     = (_Float16)v.x; w[2 * i].y     = (_Float16)v.y;
    w[2 * i + 1].x = (_Float16)v.z; w[2 * i + 1].y = (_Float16)v.w;
  }
}

// lgkm-only barrier: global stores stay in flight across regions.
__device__ __forceinline__ void lds_barrier() {
  __builtin_amdgcn_sched_barrier(0);
  asm volatile("s_waitcnt lgkmcnt(0)" ::: "memory");
  __builtin_amdgcn_s_barrier();
  __builtin_amdgcn_sched_barrier(0);
}

__device__ __forceinline__ int agpr_store(h2 v) {
  h2i u; u.h = v;
  int a;
  asm volatile("v_accvgpr_write_b32 %0, %1" : "=a"(a) : "v"(u.i));
  return a;
}
__device__ __forceinline__ h2 agpr_load(int a) {
  int t;
  asm volatile("v_accvgpr_read_b32 %0, %1" : "=v"(t) : "a"(a));
  h2i u; u.i = t;
  return u.h;
}

// ---------------------------------------------------------------------------
// Shared merged-skewed body. WPARK selects Whh1 storage: 0 = arch VGPR array,
// 1 = AGPR-parked via v_accvgpr. Structure correctness-verified in R7.
// Region u: L0 computes h0_u (reads h0b[rb]=h0_{u-1} + x_u); L1 computes
// h1_{u-1} (ih-dot shares the SAME h0b[rb] reads; hh-dot over h1b[rb]).
// Deferred head (wred) runs at u for h1_{u-2}; rotating collector emits
// out[u-3]. One lgkm-only barrier per region; 1203 regions.
// ---------------------------------------------------------------------------
template <int WPARK>
__device__ __forceinline__ void lstm_merged_body(
    const float* __restrict__ xin,
    const float* __restrict__ Wih0, const float* __restrict__ Whh0,
    const float* __restrict__ bih0, const float* __restrict__ bhh0,
    const float* __restrict__ Wih1, const float* __restrict__ Whh1,
    const float* __restrict__ bih1, const float* __restrict__ bhh1,
    const float* __restrict__ Wlin, const float* __restrict__ blin,
    float* __restrict__ out,
    __half (*xs)[T_ * I_], __half (*h0b)[H_], __half (*h1b)[H_],
    float (*red)[8])
{
  const int tid = threadIdx.x;
  const int q = tid & 3;
  const int j = tid >> 2;
  const int g = q * H_ + j;
  const int b = blockIdx.x;

  // ---- weights first (lower prologue peak), then stage xs ----
  h2 w0[64], wi[64], wx[8];
  h2 w1v[WPARK ? 1 : 64];
  int w1a[WPARK ? 64 : 1];
  load_row_h2(Whh0 + (size_t)g * H_, w0);
  load_row_h2(Wih1 + (size_t)g * H_, wi);
  if (WPARK) {
    const float* p = Whh1 + (size_t)g * H_;
#pragma unroll
    for (int i = 0; i < 32; ++i) {
      const float4 v = *(const float4*)(p + 4 * i);
      h2 t0, t1;
      t0.x = (_Float16)v.x; t0.y = (_Float16)v.y;
      t1.x = (_Float16)v.z; t1.y = (_Float16)v.w;
      w1a[2 * i] = agpr_store(t0); w1a[2 * i + 1] = agpr_store(t1);
    }
  } else {
    load_row_h2(Whh1 + (size_t)g * H_, &w1v[0]);
  }
  {
    const float* px = Wih0 + (size_t)g * I_;
#pragma unroll
    for (int i = 0; i < 4; ++i) {
      const float4 v = *(const float4*)(px + 4 * i);
      wx[2 * i].x     = (_Float16)v.x; wx[2 * i].y     = (_Float16)v.y;
      wx[2 * i + 1].x = (_Float16)v.z; wx[2 * i + 1].y = (_Float16)v.w;
    }
  }
  {
    const float4* xg4 = (const float4*)(xin + (size_t)b * T_ * I_);
    for (int idx = tid; idx < T_ * I_ / 4; idx += 512) {
      const float4 v = xg4[idx];
      (*xs)[4 * idx]     = __float2half(v.x);
      (*xs)[4 * idx + 1] = __float2half(v.y);
      (*xs)[4 * idx + 2] = __float2half(v.z);
      (*xs)[4 * idx + 3] = __float2half(v.w);
    }
  }
  const float bs0 = bih0[g] + bhh0[g];
  const float bs1 = bih1[g] + bhh1[g];
  const float wl = Wlin[j];
  const float bl = blin[0];
  const float s0 = (q == 2) ? 1.f : 0.f;
  const float s1 = (q == 2) ? -2.f : 1.f;
  const float s2 = (q == 2) ? 2.f : -1.f;

  if (tid < H_) {
    h0b[0][tid] = __float2half(0.f);
    h1b[0][tid] = __float2half(0.f);
    h1b[1][tid] = __float2half(0.f);
  }
  float cst0 = 0.f, cst1 = 0.f, hv1p = 0.f;
  float* op = out + (size_t)b * T_;
  __syncthreads();

#pragma unroll 1
  for (int u = 0; u <= T_ + 2; ++u) {
    const int rb = u & 1, nb = rb ^ 1;

    if (u >= 2 && u <= T_ + 1) {
      const float val = wred(fmaxf(hv1p, 0.f) * wl);
      if ((tid & 63) == 0) red[rb][tid >> 6] = val;
    }
    if (u >= 3) {
      const int m = u - 3;
      if (tid == ((m & 7) << 6)) {
        const float4 r0 = *(const float4*)(&red[nb][0]);
        const float4 r1 = *(const float4*)(&red[nb][4]);
        op[m] = bl + r0.x + r0.y + r0.z + r0.w + r1.x + r1.y + r1.z + r1.w;
      }
    }

    float A0 = 0.f, A1 = 0.f, A2 = 0.f, A3 = 0.f;
    float B0 = 0.f, B1 = 0.f, B2 = 0.f, B3 = 0.f;
    float C0 = 0.f, C1 = 0.f, C2 = 0.f, C3 = 0.f;

    if (u >= 1 && u < T_) {
#pragma unroll
      for (int i = 0; i < 16; ++i) {
        f16x8u u8; u8.v = *(const f16x8*)(&h0b[rb][8 * i]);
        A0 = fdot2(w0[4 * i],     u8.h[0], A0);
        A1 = fdot2(w0[4 * i + 1], u8.h[1], A1);
        A2 = fdot2(w0[4 * i + 2], u8.h[2], A2);
        A3 = fdot2(w0[4 * i + 3], u8.h[3], A3);
        B0 = fdot2(wi[4 * i],     u8.h[0], B0);
        B1 = fdot2(wi[4 * i + 1], u8.h[1], B1);
        B2 = fdot2(wi[4 * i + 2], u8.h[2], B2);
        B3 = fdot2(wi[4 * i + 3], u8.h[3], B3);
      }
    } else if (u == T_) {
#pragma unroll
      for (int i = 0; i < 16; ++i) {
        f16x8u u8; u8.v = *(const f16x8*)(&h0b[rb][8 * i]);
        B0 = fdot2(wi[4 * i],     u8.h[0], B0);
        B1 = fdot2(wi[4 * i + 1], u8.h[1], B1);
        B2 = fdot2(wi[4 * i + 2], u8.h[2], B2);
        B3 = fdot2(wi[4 * i + 3], u8.h[3], B3);
      }
    }

    if (u < T_) {
#pragma unroll
      for (int m2 = 0; m2 < 2; ++m2) {
        f16x8u u8; u8.v = *(const f16x8*)(&(*xs)[u * I_ + 8 * m2]);
        A0 = fdot2(wx[4 * m2],     u8.h[0], A0);
        A1 = fdot2(wx[4 * m2 + 1], u8.h[1], A1);
        A2 = fdot2(wx[4 * m2 + 2], u8.h[2], A2);
        A3 = fdot2(wx[4 * m2 + 3], u8.h[3], A3);
      }
      const float pre = (A0 + A1) + (A2 + A3) + bs0;
      const float act = fmaf(s1, __builtin_amdgcn_rcpf(1.f + __expf(s2 * pre)), s0);
      const float ig = qbcast<0x00>(act);
      const float fg = qbcast<0x55>(act);
      const float gg = qbcast<0xAA>(act);
      const float og = qbcast<0xFF>(act);
      cst0 = fg * cst0 + ig * gg;
      const float hv0 = og * tanh_(cst0);
      if (q == 0) h0b[nb][j] = __float2half(hv0);
    }

    if (u >= 1 && u <= T_) {
#pragma unroll
      for (int i = 0; i < 16; ++i) {
        f16x8u u8; u8.v = *(const f16x8*)(&h1b[rb][8 * i]);
        if (WPARK) {
          C0 = fdot2(agpr_load(w1a[4 * i]),     u8.h[0], C0);
          C1 = fdot2(agpr_load(w1a[4 * i + 1]), u8.h[1], C1);
          C2 = fdot2(agpr_load(w1a[4 * i + 2]), u8.h[2], C2);
          C3 = fdot2(agpr_load(w1a[4 * i + 3]), u8.h[3], C3);
        } else {
          C0 = fdot2(w1v[4 * i],     u8.h[0], C0);
          C1 = fdot2(w1v[4 * i + 1], u8.h[1], C1);
          C2 = fdot2(w1v[4 * i + 2], u8.h[2], C2);
          C3 = fdot2(w1v[4 * i + 3], u8.h[3], C3);
        }
      }
      const float pre = (B0 + B1) + (B2 + B3) + (C0 + C1) + (C2 + C3) + bs1;
      const float act = fmaf(s1, __builtin_amdgcn_rcpf(1.f + __expf(s2 * pre)), s0);
      const float ig = qbcast<0x00>(act);
      const float fg = qbcast<0x55>(act);
      const float gg = qbcast<0xAA>(act);
      const float og = qbcast<0xFF>(act);
      cst1 = fg * cst1 + ig * gg;
      hv1p = og * tanh_(cst1);
      if (q == 0) h1b[nb][j] = __float2half(hv1p);
    }

    if (u <= T_ + 1) lds_barrier();
  }
}

#define MERGED_KERNEL(NAME, WPARK)                                           \
__global__ __launch_bounds__(512, 1) void NAME(                              \
    const float* __restrict__ xin,                                           \
    const float* __restrict__ Wih0, const float* __restrict__ Whh0,          \
    const float* __restrict__ bih0, const float* __restrict__ bhh0,          \
    const float* __restrict__ Wih1, const float* __restrict__ Whh1,          \
    const float* __restrict__ bih1, const float* __restrict__ bhh1,          \
    const float* __restrict__ Wlin, const float* __restrict__ blin,          \
    float* __restrict__ out)                                                 \
{                                                                            \
  __shared__ __align__(16) __half xs[T_ * I_];                               \
  __shared__ __align__(16) __half h0b[2][H_];                                \
  __shared__ __align__(16) __half h1b[2][H_];                                \
  __shared__ __align__(16) float red[2][8];                                  \
  lstm_merged_body<WPARK>(xin, Wih0, Whh0, bih0, bhh0, Wih1, Whh1,           \
                          bih1, bhh1, Wlin, blin, out,                       \
                          &xs, h0b, h1b, red);                               \
}

MERGED_KERNEL(lstm_m1, 0)   // all weights in arch VGPRs (256-reg budget)
MERGED_KERNEL(lstm_m3, 1)   // Whh1 parked in AGPRs (arch demand ~190)

// ---------------------------------------------------------------------------
// Fallback: round-1 fused kernel (known-good, ~1750-2000 us).
// ---------------------------------------------------------------------------
__device__ __forceinline__ float qsum8f(float x) {
  x += __int_as_float(__builtin_amdgcn_update_dpp(0, __float_as_int(x), 0xB1, 0xF, 0xF, true));
  x += __int_as_float(__builtin_amdgcn_update_dpp(0, __float_as_int(x), 0x4E, 0xF, 0xF, true));
  return x;
}

__global__ __launch_bounds__(512, 2) void lstm_fused_fb(
    const float* __restrict__ xin,
    const float* __restrict__ Wih0, const float* __restrict__ Whh0,
    const float* __restrict__ bih0, const float* __restrict__ bhh0,
    const float* __restrict__ Wih1, const float* __restrict__ Whh1,
    const float* __restrict__ bih1, const float* __restrict__ bhh1,
    const float* __restrict__ Wlin, const float* __restrict__ blin,
    float* __restrict__ out)
{
  __shared__ __align__(16) __half buf0[2][H_];
  __shared__ __align__(16) __half buf1[2][H_];
  __shared__ __align__(16) float red[2][8];

  const int tid = threadIdx.x;
  const int c = tid & 3;
  const int j = tid >> 2;
  const int b = blockIdx.x;
  const int wv = tid >> 6;

  h2 w0[4][16], wi[4][16], wh[4][16];
  h2 wx[4][2];
  float bs0[4], bs1[4];

#pragma unroll
  for (int qq = 0; qq < 4; ++qq) {
    const int g = qq * H_ + j;
    const float* p0 = Whh0 + (size_t)g * H_ + c * 32;
    const float* p1 = Wih1 + (size_t)g * H_ + c * 32;
    const float* p2 = Whh1 + (size_t)g * H_ + c * 32;
#pragma unroll
    for (int i = 0; i < 8; ++i) {
      float4 v = *(const float4*)(p0 + 4 * i);
      w0[qq][2*i].x   = (_Float16)v.x; w0[qq][2*i].y   = (_Float16)v.y;
      w0[qq][2*i+1].x = (_Float16)v.z; w0[qq][2*i+1].y = (_Float16)v.w;
      v = *(const float4*)(p1 + 4 * i);
      wi[qq][2*i].x   = (_Float16)v.x; wi[qq][2*i].y   = (_Float16)v.y;
      wi[qq][2*i+1].x = (_Float16)v.z; wi[qq][2*i+1].y = (_Float16)v.w;
      v = *(const float4*)(p2 + 4 * i);
      wh[qq][2*i].x   = (_Float16)v.x; wh[qq][2*i].y   = (_Float16)v.y;
      wh[qq][2*i+1].x = (_Float16)v.z; wh[qq][2*i+1].y = (_Float16)v.w;
    }
    const float4 vx = *(const float4*)(Wih0 + (size_t)g * I_ + 4 * c);
    wx[qq][0].x = (_Float16)vx.x; wx[qq][0].y = (_Float16)vx.y;
    wx[qq][1].x = (_Float16)vx.z; wx[qq][1].y = (_Float16)vx.w;
    bs0[qq] = bih0[g] + bhh0[g];
    bs1[qq] = bih1[g] + bhh1[g];
  }
  const float wl = Wlin[j];
  const float bl = blin[0];

  if (tid < H_) {
    buf0[0][tid] = __float2half(0.f);
    buf1[0][tid] = __float2half(0.f);
  }
  float cst0 = 0.f, cst1 = 0.f;
  const float* xp = xin + (size_t)b * T_ * I_ + 4 * c;
  float* op = out + (size_t)b * T_;
  __syncthreads();

#pragma unroll 2
  for (int t = 0; t < T_; ++t) {
    const int rb = t & 1;
    const float4 xv = *(const float4*)xp; xp += I_;
    float a0 = 0.f, a1 = 0.f, a2 = 0.f, a3 = 0.f;
#pragma unroll
    for (int i = 0; i < 4; ++i) {
      f16x8u u; u.v = *(const f16x8*)(&buf0[rb][c * 32 + i * 8]);
#pragma unroll
      for (int p = 0; p < 4; ++p) {
        const h2 hv = u.h[p];
        a0 = fdot2(w0[0][4 * i + p], hv, a0);
        a1 = fdot2(w0[1][4 * i + p], hv, a1);
        a2 = fdot2(w0[2][4 * i + p], hv, a2);
        a3 = fdot2(w0[3][4 * i + p], hv, a3);
      }
    }
    h2 xa, xb;
    xa.x = (_Float16)xv.x; xa.y = (_Float16)xv.y;
    xb.x = (_Float16)xv.z; xb.y = (_Float16)xv.w;
    a0 = fdot2(wx[0][0], xa, fdot2(wx[0][1], xb, a0));
    a1 = fdot2(wx[1][0], xa, fdot2(wx[1][1], xb, a1));
    a2 = fdot2(wx[2][0], xa, fdot2(wx[2][1], xb, a2));
    a3 = fdot2(wx[3][0], xa, fdot2(wx[3][1], xb, a3));
    {
      const float g0 = qsum8f(a0) + bs0[0];
      const float g1 = qsum8f(a1) + bs0[1];
      const float g2 = qsum8f(a2) + bs0[2];
      const float g3 = qsum8f(a3) + bs0[3];
      const float ig = 1.f / (1.f + __expf(-g0));
      const float fg = 1.f / (1.f + __expf(-g1));
      const float gg = tanh_(g2);
      const float og = 1.f / (1.f + __expf(-g3));
      cst0 = fg * cst0 + ig * gg;
      const float h0v = og * tanh_(cst0);
      if (c == 0) buf0[rb ^ 1][j] = __float2half(h0v);
    }
    __syncthreads();
    a0 = 0.f; a1 = 0.f; a2 = 0.f; a3 = 0.f;
#pragma unroll
    for (int i = 0; i < 4; ++i) {
      f16x8u u; u.v = *(const f16x8*)(&buf0[rb ^ 1][c * 32 + i * 8]);
#pragma unroll
      for (int p = 0; p < 4; ++p) {
        const h2 hv = u.h[p];
        a0 = fdot2(wi[0][4 * i + p], hv, a0);
        a1 = fdot2(wi[1][4 * i + p], hv, a1);
        a2 = fdot2(wi[2][4 * i + p], hv, a2);
        a3 = fdot2(wi[3][4 * i + p], hv, a3);
      }
    }
#pragma unroll
    for (int i = 0; i < 4; ++i) {
      f16x8u u; u.v = *(const f16x8*)(&buf1[rb][c * 32 + i * 8]);
#pragma unroll
      for (int p = 0; p < 4; ++p) {
        const h2 hv = u.h[p];
        a0 = fdot2(wh[0][4 * i + p], hv, a0);
        a1 = fdot2(wh[1][4 * i + p], hv, a1);
        a2 = fdot2(wh[2][4 * i + p], hv, a2);
        a3 = fdot2(wh[3][4 * i + p], hv, a3);
      }
    }
    const float g0 = qsum8f(a0) + bs1[0];
    const float g1 = qsum8f(a1) + bs1[1];
    const float g2 = qsum8f(a2) + bs1[2];
    const float g3 = qsum8f(a3) + bs1[3];
    const float ig = 1.f / (1.f + __expf(-g0));
    const float fg = 1.f / (1.f + __expf(-g1));
    const float gg = tanh_(g2);
    const float og = 1.f / (1.f + __expf(-g3));
    cst1 = fg * cst1 + ig * gg;
    const float h1v = og * tanh_(cst1);
    if (c == 0) buf1[rb ^ 1][j] = __float2half(h1v);
    float val = wred(fmaxf(h1v, 0.f) * wl);
    if ((tid & 63) == 0) red[rb][wv] = val;
    __syncthreads();
    if (tid == ((t & 7) << 6)) {
      const float4 r0 = *(const float4*)(&red[rb][0]);
      const float4 r1 = *(const float4*)(&red[rb][4]);
      op[t] = bl + r0.x + r0.y + r0.z + r0.w + r1.x + r1.y + r1.z + r1.w;
    }
  }
}

extern "C" void kernel_launch(void* const* d_in, const int* in_sizes, int n_in,
                              void* d_out, int out_size, void* d_ws, size_t ws_size,
                              hipStream_t stream) {
  // Selector ladder (host-side attribute query; capture-safe):
  //   m1 scratch <= 256 B  -> m1 (all-arch merged; tiny/no spill)
  //   m3 scratch <= 1024 B -> m3 (AGPR-parked Whh1; prologue-scale spill ok)
  //   m1 scratch <= 4096 B -> m1 (accept prologue-scale spill; counters will
  //                               tell us next round if it was hot)
  //   else                 -> proven fallback
  static int picked = -1;
  if (picked < 0) {
    hipFuncAttributes a1{}, a3{};
    size_t s1 = (size_t)-1, s3 = (size_t)-1;
    if (hipFuncGetAttributes(&a1, reinterpret_cast<const void*>(&lstm_m1)) == hipSuccess)
      s1 = a1.localSizeBytes;
    if (hipFuncGetAttributes(&a3, reinterpret_cast<const void*>(&lstm_m3)) == hipSuccess)
      s3 = a3.localSizeBytes;
    if (s1 <= 256) picked = 1;
    else if (s3 <= 1024) picked = 3;
    else if (s1 <= 4096) picked = 1;
    else picked = 0;
  }

  if (picked == 1) {
    lstm_m1<<<B_, 512, 0, stream>>>(
        (const float*)d_in[0],
        (const float*)d_in[1], (const float*)d_in[2],
        (const float*)d_in[3], (const float*)d_in[4],
        (const float*)d_in[5], (const float*)d_in[6],
        (const float*)d_in[7], (const float*)d_in[8],
        (const float*)d_in[9], (const float*)d_in[10],
        (float*)d_out);
  } else if (picked == 3) {
    lstm_m3<<<B_, 512, 0, stream>>>(
        (const float*)d_in[0],
        (const float*)d_in[1], (const float*)d_in[2],
        (const float*)d_in[3], (const float*)d_in[4],
        (const float*)d_in[5], (const float*)d_in[6],
        (const float*)d_in[7], (const float*)d_in[8],
        (const float*)d_in[9], (const float*)d_in[10],
        (float*)d_out);
  } else {
    lstm_fused_fb<<<B_, 512, 0, stream>>>(
        (const float*)d_in[0],
        (const float*)d_in[1], (const float*)d_in[2],
        (const float*)d_in[3], (const float*)d_in[4],
        (const float*)d_in[5], (const float*)d_in[6],
        (const float*)d_in[7], (const float*)d_in[8],
        (const float*)d_in[9], (const float*)d_in[10],
        (float*)d_out);
  }
}